// Round 12
// baseline (212.168 us; speedup 1.0000x reference)
//
#include <hip/hip_runtime.h>

#define N_NODES 50000
#define N_EDGES 800000
#define F 64
#define NTILES (N_NODES / 16)                  // 3125

#define BNODES 128                             // nodes per bucket
#define NB ((N_NODES + BNODES - 1) / BNODES)   // 391 buckets
#define BCAP 2560                              // bucket capacity (mean 2046, +25% slack)
#define EPB 3200                               // edges per scatter block
#define SCAT_BLOCKS (N_EDGES / EPB)            // 250 (exact)
#define PREP_ELEMS (4 * F * F + N_NODES * 16)  // W entries + float4 groups
#define PREP_BLOCKS ((PREP_ELEMS + 511) / 512)

typedef __attribute__((ext_vector_type(8))) short short8;   // 8 bf16 (4 VGPRs)
typedef __attribute__((ext_vector_type(4))) float f32x4;    // MFMA accumulator

union frag16 { uint4 u; short8 s; };

// ---------------- bf16 helpers (storage-only; all math fp32/MFMA) ----------------

__device__ __forceinline__ float bflo(unsigned int u) {
    union { unsigned int i; float f; } c; c.i = u << 16; return c.f;
}
__device__ __forceinline__ float bfhi(unsigned int u) {
    union { unsigned int i; float f; } c; c.i = u & 0xFFFF0000u; return c.f;
}
__device__ __forceinline__ unsigned short f2bf(float f) {   // round-nearest-even
    union { float f; unsigned int i; } c; c.f = f;
    unsigned int r = c.i + 0x7FFF + ((c.i >> 16) & 1);
    return (unsigned short)(r >> 16);
}

// -------- fused: single-pass LDS-staged bucket scatter  +  W/x bf16 prep -------------
// x is stored as two half-feature tables (feats 0-31 -> xlo, 32-63 -> xhi), each
// 3.2 MB = fully L2-resident per XCD for the gather.

__global__ __launch_bounds__(512) void scatter_prep(
        const int* __restrict__ src, const int* __restrict__ dst,
        int* __restrict__ bcur, unsigned int* __restrict__ binned,
        const float* __restrict__ W0, const float* __restrict__ W1,
        const float* __restrict__ W2, const float* __restrict__ W3,
        unsigned short* __restrict__ Wt,
        const float4* __restrict__ xin,
        ushort4* __restrict__ xlo, ushort4* __restrict__ xhi) {
    if (blockIdx.x >= SCAT_BLOCKS) {
        int idx = (blockIdx.x - SCAT_BLOCKS) * 512 + threadIdx.x;
        if (idx < 4 * F * F) {
            int m = idx >> 12;
            int e = idx & 4095;
            int n = e >> 6, k = e & 63;
            const float* W = (m == 0) ? W0 : (m == 1) ? W1 : (m == 2) ? W2 : W3;
            Wt[m * F * F + n * F + k] = f2bf(W[k * F + n]);
            return;
        }
        int i = idx - 4 * F * F;
        if (i >= N_NODES * 16) return;
        float4 v = xin[i];
        ushort4 o;
        o.x = f2bf(v.x); o.y = f2bf(v.y); o.z = f2bf(v.z); o.w = f2bf(v.w);
        int node = i >> 4, c = i & 15;
        if (c < 8) xlo[node * 8 + c] = o;
        else       xhi[node * 8 + (c - 8)] = o;
        return;
    }

    __shared__ int lcnt[NB];
    __shared__ int scan[512];
    __shared__ int gbase[NB];
    __shared__ int lcur[NB];
    __shared__ unsigned int staged[EPB];
    int tid = threadIdx.x;
    int e0 = blockIdx.x * EPB;
    int e1 = min(N_EDGES, e0 + EPB);
    for (int i = tid; i < NB; i += 512) lcnt[i] = 0;
    __syncthreads();
    for (int i = e0 + tid; i < e1; i += 512)
        atomicAdd(&lcnt[dst[i] >> 7], 1);
    __syncthreads();
    int v = (tid < NB) ? lcnt[tid] : 0;
    scan[tid] = v;
    __syncthreads();
    for (int off = 1; off < 512; off <<= 1) {
        int t = (tid >= off) ? scan[tid - off] : 0;
        __syncthreads();
        scan[tid] += t;
        __syncthreads();
    }
    if (tid < NB) {
        int excl = scan[tid] - v;
        int resv = (v > 0) ? atomicAdd(&bcur[tid], v) : 0;
        gbase[tid] = tid * BCAP + resv - excl;
        lcur[tid] = excl;
    }
    __syncthreads();
    for (int i = e0 + tid; i < e1; i += 512) {
        int d = dst[i];
        int b = d >> 7;
        int dl = d & 127;
        int posl = atomicAdd(&lcur[b], 1);
        staged[posl] = (unsigned)src[i] | ((unsigned)dl << 16) | ((unsigned)b << 23);
    }
    __syncthreads();
    int cnt = e1 - e0;
    for (int i = tid; i < cnt; i += 512) {
        unsigned pk = staged[i];
        int b = pk >> 23;
        binned[gbase[b] + i] = pk;   // grouped by bucket -> mostly coalesced
    }
}

// ---- bucket_build: per bucket, node counts + local scan -> row_beg/degs/csr16 -------

__global__ __launch_bounds__(256) void bucket_build(const unsigned int* __restrict__ binned,
                                                    const int* __restrict__ bcur,
                                                    int* __restrict__ row_beg,
                                                    unsigned short* __restrict__ degs,
                                                    unsigned short* __restrict__ csr16) {
    int b = blockIdx.x;
    int start = b * BCAP;
    int cnt = bcur[b];
    __shared__ int ncnt[BNODES];
    __shared__ int nofs[BNODES];
    __shared__ int ncur[BNODES];
    int tid = threadIdx.x;
    for (int i = tid; i < BNODES; i += 256) ncnt[i] = 0;
    __syncthreads();
    for (int i = tid; i < cnt; i += 256)
        atomicAdd(&ncnt[(binned[start + i] >> 16) & 127], 1);
    __syncthreads();
    if (tid < 128) nofs[tid] = ncnt[tid];
    __syncthreads();
    for (int off = 1; off < 128; off <<= 1) {
        int t = (tid >= off && tid < 128) ? nofs[tid - off] : 0;
        __syncthreads();
        if (tid < 128) nofs[tid] += t;
        __syncthreads();
    }
    if (tid < 128) {
        int excl = nofs[tid] - ncnt[tid];
        ncur[tid] = excl;
        int node = b * BNODES + tid;
        row_beg[node] = start + excl;
        degs[node] = (unsigned short)ncnt[tid];
    }
    __syncthreads();
    for (int i = tid; i < cnt; i += 256) {
        unsigned pk = binned[start + i];
        int dl = (pk >> 16) & 127;
        int pos = start + atomicAdd(&ncur[dl], 1);
        csr16[pos] = (unsigned short)(pk & 0xFFFF);
    }
}

// ------ aggregation over half-tables: task = (half, node); 16 groups x 4 lanes x 16B -
// Tasks [0, N) gather the lo table, [N, 2N) the hi table. Sequential dispatch means
// each XCD mostly drains lo before hi -> one 3.2 MB table hot in L2 at a time.
// All 16 avg-degree edges issue in ONE wave instruction (16 rows x 64B).

__global__ __launch_bounds__(256) void aggregate_kernel(
        const uint4* __restrict__ xlo, const uint4* __restrict__ xhi,
        const int* __restrict__ row_beg, const unsigned short* __restrict__ degs,
        const unsigned short* __restrict__ csr16,
        uint4* __restrict__ alo, uint4* __restrict__ ahi) {
    int wave = threadIdx.x >> 6;
    int lane = threadIdx.x & 63;
    int task = blockIdx.x * 4 + wave;
    if (task >= 2 * N_NODES) return;
    int half = (task >= N_NODES);
    int node = task - half * N_NODES;
    const uint4* tbl = half ? xhi : xlo;
    uint4* outt = half ? ahi : alo;

    int g   = lane >> 2;    // edge group 0..15
    int sub = lane & 3;     // ushort8 (8 feats, 16B) within the 32-feat half-row
    int beg = row_beg[node];
    int deg = degs[node];
    int end = beg + deg;
    float a[8];
    #pragma unroll
    for (int j = 0; j < 8; ++j) a[j] = 0.f;
    for (int i = beg + g; i < end; i += 16) {
        int i0 = csr16[i];
        uint4 v = tbl[i0 * 4 + sub];
        a[0] += bflo(v.x); a[1] += bfhi(v.x); a[2] += bflo(v.y); a[3] += bfhi(v.y);
        a[4] += bflo(v.z); a[5] += bfhi(v.z); a[6] += bflo(v.w); a[7] += bfhi(v.w);
    }
    #pragma unroll
    for (int off = 4; off <= 32; off <<= 1)
        #pragma unroll
        for (int j = 0; j < 8; ++j)
            a[j] += __shfl_xor(a[j], off);
    if (g == 0) {
        float inv = (deg > 0) ? (1.0f / (float)deg) : 0.f;
        unsigned short o[8];
        #pragma unroll
        for (int j = 0; j < 8; ++j) o[j] = f2bf(a[j] * inv);
        uint4 pk;
        pk.x = (unsigned)o[0] | ((unsigned)o[1] << 16);
        pk.y = (unsigned)o[2] | ((unsigned)o[3] << 16);
        pk.z = (unsigned)o[4] | ((unsigned)o[5] << 16);
        pk.w = (unsigned)o[6] | ((unsigned)o[7] << 16);
        outt[node * 4 + sub] = pk;
    }
}

// ---------------- MFMA transform: h = relu(x@Ws + agg@Wn + b) ------------------------
// One wave per 16-node m-tile, no LDS. Split tables are transparent:
// kt=0 A-frags (k 0-31) come from lo, kt=1 from hi. Output written as split halves.

__global__ __launch_bounds__(256) void mfma_transform(
        const uint4* __restrict__ xlo, const uint4* __restrict__ xhi,
        const uint4* __restrict__ alo, const uint4* __restrict__ ahi,
        const uint4* __restrict__ Wst, const uint4* __restrict__ Wnt,
        const float* __restrict__ b,
        unsigned short* __restrict__ out_lo, unsigned short* __restrict__ out_hi,
        const float* __restrict__ Ws3, const float* __restrict__ Wn3,
        float* __restrict__ pout, float* __restrict__ qout, int ntiles) {
    int wv   = threadIdx.x >> 6;
    int lane = threadIdx.x & 63;
    int tile = blockIdx.x * 4 + wv;
    if (tile >= ntiles) return;
    int lo = lane & 15, hi = lane >> 4;

    frag16 ws[2][4], wn[2][4];
    #pragma unroll
    for (int kt = 0; kt < 2; ++kt)
        #pragma unroll
        for (int jt = 0; jt < 4; ++jt) {
            int n = jt * 16 + lo;
            ws[kt][jt].u = Wst[n * 8 + kt * 4 + hi];
            wn[kt][jt].u = Wnt[n * 8 + kt * 4 + hi];
        }

    float bias_s[4];
    #pragma unroll
    for (int jt = 0; jt < 4; ++jt) bias_s[jt] = b[jt * 16 + lo];
    float w3n_s[4], w3s_s[4];
    if (pout) {
        #pragma unroll
        for (int jt = 0; jt < 4; ++jt) {
            w3n_s[jt] = Wn3[jt * 16 + lo];
            w3s_s[jt] = Ws3[jt * 16 + lo];
        }
    }

    int base = tile * 16;
    int node = base + lo;

    frag16 ax[2], aa[2];
    ax[0].u = xlo[node * 4 + hi];
    ax[1].u = xhi[node * 4 + hi];
    aa[0].u = alo[node * 4 + hi];
    aa[1].u = ahi[node * 4 + hi];

    f32x4 acc[4];
    #pragma unroll
    for (int jt = 0; jt < 4; ++jt)
        acc[jt] = f32x4{bias_s[jt], bias_s[jt], bias_s[jt], bias_s[jt]};

    #pragma unroll
    for (int kt = 0; kt < 2; ++kt)
        #pragma unroll
        for (int jt = 0; jt < 4; ++jt) {
            acc[jt] = __builtin_amdgcn_mfma_f32_16x16x32_bf16(ax[kt].s, ws[kt][jt].s, acc[jt], 0, 0, 0);
            acc[jt] = __builtin_amdgcn_mfma_f32_16x16x32_bf16(aa[kt].s, wn[kt][jt].s, acc[jt], 0, 0, 0);
        }

    if (out_lo) {
        #pragma unroll
        for (int jt = 0; jt < 4; ++jt) {
            unsigned short* otbl = (jt < 2) ? out_lo : out_hi;
            int col = (jt & 1) * 16 + lo;
            #pragma unroll
            for (int r = 0; r < 4; ++r) {
                float h = fmaxf(acc[jt][r], 0.f);
                otbl[(base + hi * 4 + r) * 32 + col] = f2bf(h);
            }
        }
    } else {
        #pragma unroll
        for (int r = 0; r < 4; ++r) {
            float pr = 0.f, qr = 0.f;
            #pragma unroll
            for (int jt = 0; jt < 4; ++jt) {
                float h = fmaxf(acc[jt][r], 0.f);
                pr += h * w3n_s[jt];
                qr += h * w3s_s[jt];
            }
            #pragma unroll
            for (int off = 1; off < 16; off <<= 1) {
                pr += __shfl_xor(pr, off);
                qr += __shfl_xor(qr, off);
            }
            if (lo == 0) {
                pout[base + hi * 4 + r] = pr;
                qout[base + hi * 4 + r] = qr;
            }
        }
    }
}

// ---------------- final: out = q + mean_agg(p) + b3, 16 lanes per node ----------------

__global__ __launch_bounds__(256) void final_kernel(
        const int* __restrict__ row_beg, const unsigned short* __restrict__ degs,
        const unsigned short* __restrict__ csr16,
        const float* __restrict__ p, const float* __restrict__ q,
        const float* __restrict__ b3, float* __restrict__ out, int n_nodes) {
    int grp = threadIdx.x >> 4;
    int ln  = threadIdx.x & 15;
    int node = blockIdx.x * 16 + grp;
    if (node >= n_nodes) return;
    int beg = row_beg[node];
    int deg = degs[node];
    int end = beg + deg;
    float s = 0.f;
    for (int i = beg + ln; i < end; i += 16) s += p[csr16[i]];
    #pragma unroll
    for (int off = 1; off < 16; off <<= 1) s += __shfl_xor(s, off);
    if (ln == 0) {
        float inv = (deg > 0) ? (1.0f / (float)deg) : 0.f;
        out[node] = q[node] + s * inv + b3[0];
    }
}

// ---------------- launch ----------------

extern "C" void kernel_launch(void* const* d_in, const int* in_sizes, int n_in,
                              void* d_out, int out_size, void* d_ws, size_t ws_size,
                              hipStream_t stream) {
    const float* x   = (const float*)d_in[0];
    const int*   src = (const int*)d_in[1];
    const int*   dst = (const int*)d_in[2];
    const float* Ws1 = (const float*)d_in[3];
    const float* Wn1 = (const float*)d_in[4];
    const float* b1  = (const float*)d_in[5];
    const float* Ws2 = (const float*)d_in[6];
    const float* Wn2 = (const float*)d_in[7];
    const float* b2  = (const float*)d_in[8];
    const float* Ws3 = (const float*)d_in[9];
    const float* Wn3 = (const float*)d_in[10];
    const float* b3  = (const float*)d_in[11];
    float* out = (float*)d_out;

    char* ws = (char*)d_ws;
    size_t cur = 0;
    auto alloc = [&](size_t bytes) -> void* {
        void* p = ws + cur;
        cur += (bytes + 255) & ~(size_t)255;
        return p;
    };

    const size_t HT = (size_t)N_NODES * 32 * 2;   // half-table bytes (3.2 MB)

    int*            bcur     = (int*)  alloc(NB * sizeof(int));
    unsigned int*   binned   = (unsigned int*)alloc((size_t)NB * BCAP * sizeof(unsigned int));
    int*            row_beg  = (int*)  alloc((size_t)(NB * BNODES) * sizeof(int));
    unsigned short* degs     = (unsigned short*)alloc((size_t)(NB * BNODES) * sizeof(unsigned short));
    unsigned short* csr16    = (unsigned short*)alloc((size_t)NB * BCAP * sizeof(unsigned short));
    unsigned short* xlo      = (unsigned short*)alloc(HT);
    unsigned short* xhi      = (unsigned short*)alloc(HT);
    unsigned short* h1lo     = (unsigned short*)alloc(HT);
    unsigned short* h1hi     = (unsigned short*)alloc(HT);
    unsigned short* aglo     = (unsigned short*)alloc(HT);
    unsigned short* aghi     = (unsigned short*)alloc(HT);
    unsigned short* Wt       = (unsigned short*)alloc(4 * F * F * 2);   // bf16 W^T x4
    float*          p        = (float*)alloc(N_NODES * sizeof(float));
    float*          q        = (float*)alloc(N_NODES * sizeof(float));

    unsigned short* Wst1 = Wt;
    unsigned short* Wnt1 = Wt + F * F;
    unsigned short* Wst2 = Wt + 2 * F * F;
    unsigned short* Wnt2 = Wt + 3 * F * F;

    // single-pass binned CSR build + prep (fused)
    (void)hipMemsetAsync(bcur, 0, NB * sizeof(int), stream);
    scatter_prep<<<SCAT_BLOCKS + PREP_BLOCKS, 512, 0, stream>>>(
        src, dst, bcur, binned,
        Ws1, Wn1, Ws2, Wn2, Wt, (const float4*)x, (ushort4*)xlo, (ushort4*)xhi);
    bucket_build<<<NB, 256, 0, stream>>>(binned, bcur, row_beg, degs, csr16);

    int agg_grid = (2 * N_NODES + 3) / 4;   // 25000 (lo tasks first, then hi)
    int tf_grid  = (NTILES + 3) / 4;        // 782

    // layer 1
    aggregate_kernel<<<agg_grid, 256, 0, stream>>>(
        (const uint4*)xlo, (const uint4*)xhi, row_beg, degs, csr16,
        (uint4*)aglo, (uint4*)aghi);
    mfma_transform<<<tf_grid, 256, 0, stream>>>(
        (const uint4*)xlo, (const uint4*)xhi, (const uint4*)aglo, (const uint4*)aghi,
        (const uint4*)Wst1, (const uint4*)Wnt1, b1,
        h1lo, h1hi, nullptr, nullptr, nullptr, nullptr, NTILES);
    // layer 2 (+ fused layer-3 projection)
    aggregate_kernel<<<agg_grid, 256, 0, stream>>>(
        (const uint4*)h1lo, (const uint4*)h1hi, row_beg, degs, csr16,
        (uint4*)aglo, (uint4*)aghi);
    mfma_transform<<<tf_grid, 256, 0, stream>>>(
        (const uint4*)h1lo, (const uint4*)h1hi, (const uint4*)aglo, (const uint4*)aghi,
        (const uint4*)Wst2, (const uint4*)Wnt2, b2,
        nullptr, nullptr, Ws3, Wn3, p, q, NTILES);
    // layer 3: aggregate scalars
    final_kernel<<<(N_NODES + 15) / 16, 256, 0, stream>>>(
        row_beg, degs, csr16, p, q, b3, out, N_NODES);
}

// Round 13
// 177.865 us; speedup vs baseline: 1.1929x; 1.1929x over previous
//
#include <hip/hip_runtime.h>

#define N_NODES 50000
#define N_EDGES 800000
#define F 64
#define NTILES (N_NODES / 16)                  // 3125

#define BNODES 128                             // nodes per bucket
#define NB ((N_NODES + BNODES - 1) / BNODES)   // 391 buckets
#define BCAP 2560                              // bucket capacity (mean 2046, +25% slack)
#define EPB 3200                               // edges per scatter block
#define SCAT_BLOCKS (N_EDGES / EPB)            // 250 (exact)
#define PREP_ELEMS (4 * F * F + N_NODES * 16)  // W entries + float4 groups
#define PREP_BLOCKS ((PREP_ELEMS + 511) / 512)

typedef __attribute__((ext_vector_type(8))) short short8;   // 8 bf16 (4 VGPRs)
typedef __attribute__((ext_vector_type(4))) float f32x4;    // MFMA accumulator

union frag16 { uint4 u; short8 s; };

// ---------------- bf16 helpers (storage-only; all math fp32/MFMA) ----------------

__device__ __forceinline__ float bflo(unsigned int u) {
    union { unsigned int i; float f; } c; c.i = u << 16; return c.f;
}
__device__ __forceinline__ float bfhi(unsigned int u) {
    union { unsigned int i; float f; } c; c.i = u & 0xFFFF0000u; return c.f;
}
__device__ __forceinline__ unsigned short f2bf(float f) {   // round-nearest-even
    union { float f; unsigned int i; } c; c.f = f;
    unsigned int r = c.i + 0x7FFF + ((c.i >> 16) & 1);
    return (unsigned short)(r >> 16);
}

// -------- fused: single-pass LDS-staged bucket scatter  +  W/x bf16 prep -------------
// scatter blocks (blockIdx < SCAT_BLOCKS): stage EPB edges, group by bucket in LDS,
// reserve [b*BCAP + atomicAdd(bcur[b], v)] ranges, write grouped.
// prep blocks: W fp32[k][n] -> bf16 W^T[n][k] (4 mats), then x fp32 -> bf16.
// packed edge: src (bits 0-15) | dst_local (bits 16-22) | bucket (bits 23-31)

__global__ __launch_bounds__(512) void scatter_prep(
        const int* __restrict__ src, const int* __restrict__ dst,
        int* __restrict__ bcur, unsigned int* __restrict__ binned,
        const float* __restrict__ W0, const float* __restrict__ W1,
        const float* __restrict__ W2, const float* __restrict__ W3,
        unsigned short* __restrict__ Wt,
        const float4* __restrict__ xin, ushort4* __restrict__ xout) {
    if (blockIdx.x >= SCAT_BLOCKS) {
        int idx = (blockIdx.x - SCAT_BLOCKS) * 512 + threadIdx.x;
        if (idx < 4 * F * F) {
            int m = idx >> 12;
            int e = idx & 4095;
            int n = e >> 6, k = e & 63;
            const float* W = (m == 0) ? W0 : (m == 1) ? W1 : (m == 2) ? W2 : W3;
            Wt[m * F * F + n * F + k] = f2bf(W[k * F + n]);
            return;
        }
        int i = idx - 4 * F * F;
        if (i >= N_NODES * 16) return;
        float4 v = xin[i];
        ushort4 o;
        o.x = f2bf(v.x); o.y = f2bf(v.y); o.z = f2bf(v.z); o.w = f2bf(v.w);
        xout[i] = o;
        return;
    }

    __shared__ int lcnt[NB];
    __shared__ int scan[512];
    __shared__ int gbase[NB];
    __shared__ int lcur[NB];
    __shared__ unsigned int staged[EPB];
    int tid = threadIdx.x;
    int e0 = blockIdx.x * EPB;
    int e1 = min(N_EDGES, e0 + EPB);
    for (int i = tid; i < NB; i += 512) lcnt[i] = 0;
    __syncthreads();
    for (int i = e0 + tid; i < e1; i += 512)
        atomicAdd(&lcnt[dst[i] >> 7], 1);
    __syncthreads();
    int v = (tid < NB) ? lcnt[tid] : 0;
    scan[tid] = v;
    __syncthreads();
    for (int off = 1; off < 512; off <<= 1) {
        int t = (tid >= off) ? scan[tid - off] : 0;
        __syncthreads();
        scan[tid] += t;
        __syncthreads();
    }
    if (tid < NB) {
        int excl = scan[tid] - v;
        int resv = (v > 0) ? atomicAdd(&bcur[tid], v) : 0;
        gbase[tid] = tid * BCAP + resv - excl;
        lcur[tid] = excl;
    }
    __syncthreads();
    for (int i = e0 + tid; i < e1; i += 512) {
        int d = dst[i];
        int b = d >> 7;
        int dl = d & 127;
        int posl = atomicAdd(&lcur[b], 1);
        staged[posl] = (unsigned)src[i] | ((unsigned)dl << 16) | ((unsigned)b << 23);
    }
    __syncthreads();
    int cnt = e1 - e0;
    for (int i = tid; i < cnt; i += 512) {
        unsigned pk = staged[i];
        int b = pk >> 23;
        binned[gbase[b] + i] = pk;   // grouped by bucket -> mostly coalesced
    }
}

// ---- bucket_build: per bucket, node counts + local scan -> row_beg/degs/csr16 -------

__global__ __launch_bounds__(256) void bucket_build(const unsigned int* __restrict__ binned,
                                                    const int* __restrict__ bcur,
                                                    int* __restrict__ row_beg,
                                                    unsigned short* __restrict__ degs,
                                                    unsigned short* __restrict__ csr16) {
    int b = blockIdx.x;
    int start = b * BCAP;
    int cnt = bcur[b];
    __shared__ int ncnt[BNODES];
    __shared__ int nofs[BNODES];
    __shared__ int ncur[BNODES];
    int tid = threadIdx.x;
    for (int i = tid; i < BNODES; i += 256) ncnt[i] = 0;
    __syncthreads();
    for (int i = tid; i < cnt; i += 256)
        atomicAdd(&ncnt[(binned[start + i] >> 16) & 127], 1);
    __syncthreads();
    if (tid < 128) nofs[tid] = ncnt[tid];
    __syncthreads();
    for (int off = 1; off < 128; off <<= 1) {
        int t = (tid >= off && tid < 128) ? nofs[tid - off] : 0;
        __syncthreads();
        if (tid < 128) nofs[tid] += t;
        __syncthreads();
    }
    if (tid < 128) {
        int excl = nofs[tid] - ncnt[tid];
        ncur[tid] = excl;
        int node = b * BNODES + tid;
        row_beg[node] = start + excl;
        degs[node] = (unsigned short)ncnt[tid];
    }
    __syncthreads();
    for (int i = tid; i < cnt; i += 256) {
        unsigned pk = binned[start + i];
        int dl = (pk >> 16) & 127;
        int pos = start + atomicAdd(&ncur[dl], 1);
        csr16[pos] = (unsigned short)(pk & 0xFFFF);
    }
}

// ------------- aggregation: wave/node, 8 groups x 8 lanes x ushort8 (16B), 2 chains --

__global__ __launch_bounds__(256) void aggregate_kernel(
        const uint4* __restrict__ xh8, const int* __restrict__ row_beg,
        const unsigned short* __restrict__ degs,
        const unsigned short* __restrict__ csr16, uint4* __restrict__ aggh8, int n_nodes) {
    int wave = threadIdx.x >> 6;
    int lane = threadIdx.x & 63;
    int node = blockIdx.x * 4 + wave;
    if (node >= n_nodes) return;
    int g   = lane >> 3;    // edge group 0..7
    int sub = lane & 7;     // ushort8 (8 feats, 16B) within the 64-feat row
    int beg = row_beg[node];
    int deg = degs[node];
    int end = beg + deg;
    float a0[8], a1[8];
    #pragma unroll
    for (int j = 0; j < 8; ++j) { a0[j] = 0.f; a1[j] = 0.f; }
    int i = beg + g;
    for (; i + 8 < end; i += 16) {   // 2 chains x 8 groups = 16 edges in flight
        int i0 = csr16[i];
        int i1 = csr16[i + 8];
        uint4 v0 = xh8[i0 * 8 + sub];
        uint4 v1 = xh8[i1 * 8 + sub];
        a0[0] += bflo(v0.x); a0[1] += bfhi(v0.x); a0[2] += bflo(v0.y); a0[3] += bfhi(v0.y);
        a0[4] += bflo(v0.z); a0[5] += bfhi(v0.z); a0[6] += bflo(v0.w); a0[7] += bfhi(v0.w);
        a1[0] += bflo(v1.x); a1[1] += bfhi(v1.x); a1[2] += bflo(v1.y); a1[3] += bfhi(v1.y);
        a1[4] += bflo(v1.z); a1[5] += bfhi(v1.z); a1[6] += bflo(v1.w); a1[7] += bfhi(v1.w);
    }
    if (i < end) {
        uint4 v0 = xh8[csr16[i] * 8 + sub];
        a0[0] += bflo(v0.x); a0[1] += bfhi(v0.x); a0[2] += bflo(v0.y); a0[3] += bfhi(v0.y);
        a0[4] += bflo(v0.z); a0[5] += bfhi(v0.z); a0[6] += bflo(v0.w); a0[7] += bfhi(v0.w);
    }
    float s[8];
    #pragma unroll
    for (int j = 0; j < 8; ++j) s[j] = a0[j] + a1[j];
    #pragma unroll
    for (int off = 8; off <= 32; off <<= 1)
        #pragma unroll
        for (int j = 0; j < 8; ++j)
            s[j] += __shfl_xor(s[j], off);
    if (g == 0) {
        float inv = (deg > 0) ? (1.0f / (float)deg) : 0.f;
        unsigned short o[8];
        #pragma unroll
        for (int j = 0; j < 8; ++j) o[j] = f2bf(s[j] * inv);
        uint4 pk;
        pk.x = (unsigned)o[0] | ((unsigned)o[1] << 16);
        pk.y = (unsigned)o[2] | ((unsigned)o[3] << 16);
        pk.z = (unsigned)o[4] | ((unsigned)o[5] << 16);
        pk.w = (unsigned)o[6] | ((unsigned)o[7] << 16);
        aggh8[node * 8 + sub] = pk;
    }
}

// ---------------- MFMA transform: h = relu(x@Ws + agg@Wn + b) ------------------------
// One wave per 16-node m-tile, no LDS (R7/R10 known-good).

__global__ __launch_bounds__(256) void mfma_transform(
        const uint4* __restrict__ xh, const uint4* __restrict__ aggh,
        const uint4* __restrict__ Wst, const uint4* __restrict__ Wnt,
        const float* __restrict__ b,
        unsigned short* __restrict__ out_bf,
        const float* __restrict__ Ws3, const float* __restrict__ Wn3,
        float* __restrict__ pout, float* __restrict__ qout, int ntiles) {
    int wv   = threadIdx.x >> 6;
    int lane = threadIdx.x & 63;
    int tile = blockIdx.x * 4 + wv;
    if (tile >= ntiles) return;
    int lo = lane & 15, hi = lane >> 4;

    frag16 ws[2][4], wn[2][4];
    #pragma unroll
    for (int kt = 0; kt < 2; ++kt)
        #pragma unroll
        for (int jt = 0; jt < 4; ++jt) {
            int n = jt * 16 + lo;
            ws[kt][jt].u = Wst[n * 8 + kt * 4 + hi];
            wn[kt][jt].u = Wnt[n * 8 + kt * 4 + hi];
        }

    float bias_s[4];
    #pragma unroll
    for (int jt = 0; jt < 4; ++jt) bias_s[jt] = b[jt * 16 + lo];
    float w3n_s[4], w3s_s[4];
    if (pout) {
        #pragma unroll
        for (int jt = 0; jt < 4; ++jt) {
            w3n_s[jt] = Wn3[jt * 16 + lo];
            w3s_s[jt] = Ws3[jt * 16 + lo];
        }
    }

    int base = tile * 16;
    int node = base + lo;

    frag16 ax[2], aa[2];
    #pragma unroll
    for (int kt = 0; kt < 2; ++kt) {
        ax[kt].u = xh[node * 8 + kt * 4 + hi];
        aa[kt].u = aggh[node * 8 + kt * 4 + hi];
    }

    f32x4 acc[4];
    #pragma unroll
    for (int jt = 0; jt < 4; ++jt)
        acc[jt] = f32x4{bias_s[jt], bias_s[jt], bias_s[jt], bias_s[jt]};

    #pragma unroll
    for (int kt = 0; kt < 2; ++kt)
        #pragma unroll
        for (int jt = 0; jt < 4; ++jt) {
            acc[jt] = __builtin_amdgcn_mfma_f32_16x16x32_bf16(ax[kt].s, ws[kt][jt].s, acc[jt], 0, 0, 0);
            acc[jt] = __builtin_amdgcn_mfma_f32_16x16x32_bf16(aa[kt].s, wn[kt][jt].s, acc[jt], 0, 0, 0);
        }

    if (out_bf) {
        #pragma unroll
        for (int jt = 0; jt < 4; ++jt)
            #pragma unroll
            for (int r = 0; r < 4; ++r) {
                float h = fmaxf(acc[jt][r], 0.f);
                out_bf[(base + hi * 4 + r) * F + jt * 16 + lo] = f2bf(h);
            }
    } else {
        #pragma unroll
        for (int r = 0; r < 4; ++r) {
            float pr = 0.f, qr = 0.f;
            #pragma unroll
            for (int jt = 0; jt < 4; ++jt) {
                float h = fmaxf(acc[jt][r], 0.f);
                pr += h * w3n_s[jt];
                qr += h * w3s_s[jt];
            }
            #pragma unroll
            for (int off = 1; off < 16; off <<= 1) {
                pr += __shfl_xor(pr, off);
                qr += __shfl_xor(qr, off);
            }
            if (lo == 0) {
                pout[base + hi * 4 + r] = pr;
                qout[base + hi * 4 + r] = qr;
            }
        }
    }
}

// ---------------- final: out = q + mean_agg(p) + b3, 16 lanes per node ----------------

__global__ __launch_bounds__(256) void final_kernel(
        const int* __restrict__ row_beg, const unsigned short* __restrict__ degs,
        const unsigned short* __restrict__ csr16,
        const float* __restrict__ p, const float* __restrict__ q,
        const float* __restrict__ b3, float* __restrict__ out, int n_nodes) {
    int grp = threadIdx.x >> 4;
    int ln  = threadIdx.x & 15;
    int node = blockIdx.x * 16 + grp;
    if (node >= n_nodes) return;
    int beg = row_beg[node];
    int deg = degs[node];
    int end = beg + deg;
    float s = 0.f;
    for (int i = beg + ln; i < end; i += 16) s += p[csr16[i]];
    #pragma unroll
    for (int off = 1; off < 16; off <<= 1) s += __shfl_xor(s, off);
    if (ln == 0) {
        float inv = (deg > 0) ? (1.0f / (float)deg) : 0.f;
        out[node] = q[node] + s * inv + b3[0];
    }
}

// ---------------- launch ----------------

extern "C" void kernel_launch(void* const* d_in, const int* in_sizes, int n_in,
                              void* d_out, int out_size, void* d_ws, size_t ws_size,
                              hipStream_t stream) {
    const float* x   = (const float*)d_in[0];
    const int*   src = (const int*)d_in[1];
    const int*   dst = (const int*)d_in[2];
    const float* Ws1 = (const float*)d_in[3];
    const float* Wn1 = (const float*)d_in[4];
    const float* b1  = (const float*)d_in[5];
    const float* Ws2 = (const float*)d_in[6];
    const float* Wn2 = (const float*)d_in[7];
    const float* b2  = (const float*)d_in[8];
    const float* Ws3 = (const float*)d_in[9];
    const float* Wn3 = (const float*)d_in[10];
    const float* b3  = (const float*)d_in[11];
    float* out = (float*)d_out;

    char* ws = (char*)d_ws;
    size_t cur = 0;
    auto alloc = [&](size_t bytes) -> void* {
        void* p = ws + cur;
        cur += (bytes + 255) & ~(size_t)255;
        return p;
    };

    int*            bcur     = (int*)  alloc(NB * sizeof(int));
    unsigned int*   binned   = (unsigned int*)alloc((size_t)NB * BCAP * sizeof(unsigned int));
    int*            row_beg  = (int*)  alloc((size_t)(NB * BNODES) * sizeof(int));
    unsigned short* degs     = (unsigned short*)alloc((size_t)(NB * BNODES) * sizeof(unsigned short));
    unsigned short* csr16    = (unsigned short*)alloc((size_t)NB * BCAP * sizeof(unsigned short));
    unsigned short* xh       = (unsigned short*)alloc((size_t)N_NODES * F * 2);  // bf16 x
    unsigned short* h1h      = (unsigned short*)alloc((size_t)N_NODES * F * 2);  // bf16 h1
    unsigned short* aggh     = (unsigned short*)alloc((size_t)N_NODES * F * 2);  // bf16 agg
    unsigned short* Wt       = (unsigned short*)alloc(4 * F * F * 2);            // bf16 W^T x4
    float*          p        = (float*)alloc(N_NODES * sizeof(float));
    float*          q        = (float*)alloc(N_NODES * sizeof(float));

    unsigned short* Wst1 = Wt;
    unsigned short* Wnt1 = Wt + F * F;
    unsigned short* Wst2 = Wt + 2 * F * F;
    unsigned short* Wnt2 = Wt + 3 * F * F;

    // single-pass binned CSR build + prep (fused)
    (void)hipMemsetAsync(bcur, 0, NB * sizeof(int), stream);
    scatter_prep<<<SCAT_BLOCKS + PREP_BLOCKS, 512, 0, stream>>>(
        src, dst, bcur, binned,
        Ws1, Wn1, Ws2, Wn2, Wt, (const float4*)x, (ushort4*)xh);
    bucket_build<<<NB, 256, 0, stream>>>(binned, bcur, row_beg, degs, csr16);

    int agg_grid = (N_NODES + 3) / 4;
    int tf_grid  = (NTILES + 3) / 4;   // 782

    // layer 1
    aggregate_kernel<<<agg_grid, 256, 0, stream>>>(
        (const uint4*)xh, row_beg, degs, csr16, (uint4*)aggh, N_NODES);
    mfma_transform<<<tf_grid, 256, 0, stream>>>(
        (const uint4*)xh, (const uint4*)aggh, (const uint4*)Wst1, (const uint4*)Wnt1,
        b1, h1h, nullptr, nullptr, nullptr, nullptr, NTILES);
    // layer 2 (+ fused layer-3 projection)
    aggregate_kernel<<<agg_grid, 256, 0, stream>>>(
        (const uint4*)h1h, row_beg, degs, csr16, (uint4*)aggh, N_NODES);
    mfma_transform<<<tf_grid, 256, 0, stream>>>(
        (const uint4*)h1h, (const uint4*)aggh, (const uint4*)Wst2, (const uint4*)Wnt2,
        b2, nullptr, Ws3, Wn3, p, q, NTILES);
    // layer 3: aggregate scalars
    final_kernel<<<(N_NODES + 15) / 16, 256, 0, stream>>>(
        row_beg, degs, csr16, p, q, b3, out, N_NODES);
}